// Round 9
// baseline (545.330 us; speedup 1.0000x reference)
//
#include <hip/hip_runtime.h>

typedef unsigned short u16;
typedef __attribute__((ext_vector_type(8))) short bf16x8;
typedef __attribute__((ext_vector_type(4))) float f32x4;

__device__ __forceinline__ float bf2f(u16 u) { return __uint_as_float(((unsigned)u) << 16); }
__device__ __forceinline__ u16 f2bf(float f) {
    unsigned u = __float_as_uint(f);
    return (u16)((u + 0x7FFFu + ((u >> 16) & 1u)) >> 16);
}

// fast GELU (tanh form): v * sigmoid(1.5957691*v + 0.07135481*v^3)
__device__ __forceinline__ float gelu_fast(float v) {
    float u = v * (1.5957691216057308f + 0.07135481282700722f * v * v);
    return v * (1.f / (1.f + __expf(-u)));
}

// async global->LDS, 16 B per lane. LDS dest = wave-uniform base + lane*16.
__device__ __forceinline__ void load_lds16(const u16* g, u16* l) {
    __builtin_amdgcn_global_load_lds(
        (const __attribute__((address_space(1))) unsigned int*)g,
        (__attribute__((address_space(3))) unsigned int*)l,
        16, 0, 0);
}

// ---------------------------------------------------------------------------
// gemm3: K=256 specialized, barrier-free M-loop.
// W pre-swizzled (wswz): per 128-col panel, contiguous 64 KB of 16B groups
// group idx (kq_glob*128 + n), group = W^T[n][kq_glob*8 .. +8].
// Block: stage whole B panel once (1 barrier), then RT row-tiles of 128 rows:
// A streamed global->VGPR via depth-2 ring, B frags from LDS (0 conflicts).
// EPI 0: +bias, bf16 out   1: +bias+res(f32), f32 out   2: +bias+gelu, bf16
// ---------------------------------------------------------------------------
template<int RT, int EPI>
__global__ __launch_bounds__(256, 2) void gemm3_kernel(
    const u16* __restrict__ A, const u16* __restrict__ Wsw,
    const float* __restrict__ bias, const float* __restrict__ res,
    void* __restrict__ outp, int M, int N)
{
    __shared__ __align__(16) u16 Bs[128 * 256];   // 64 KB panel
    const int tid  = threadIdx.x;
    const int lane = tid & 63;
    const int wave = tid >> 6;
    const int pan  = blockIdx.y;
    const int rowS = blockIdx.x * (RT * 128);
    const int wr = (wave >> 1) * 64;
    const int wc = (wave & 1) * 64;
    const int lr = lane & 15;
    const int kq = lane >> 4;                     // 0..3

    // stage whole B panel: 16 sweeps x 256 threads x 16 B (contiguous)
    const u16* wsrc = Wsw + (size_t)pan * (256 * 128);
#pragma unroll
    for (int p = 0; p < 16; ++p)
        load_lds16(wsrc + p * 2048 + tid * 8, Bs + p * 2048 + tid * 8);
    __syncthreads();                              // only barrier in the kernel

    const int col00 = pan * 128;
    for (int rt = 0; rt < RT; ++rt) {
        const int row0 = rowS + rt * 128;
        const u16* arow = A + (size_t)(row0 + wr + lr) * 256 + kq * 8;

        f32x4 acc[4][4];
#pragma unroll
        for (int i = 0; i < 4; ++i)
#pragma unroll
            for (int j = 0; j < 4; ++j) acc[i][j] = (f32x4){0.f, 0.f, 0.f, 0.f};

        bf16x8 af[3][4];                          // depth-2 prefetch ring
#pragma unroll
        for (int i = 0; i < 4; ++i) af[0][i] = *(const bf16x8*)(arow + (size_t)i * 16 * 256);
#pragma unroll
        for (int i = 0; i < 4; ++i) af[1][i] = *(const bf16x8*)(arow + (size_t)i * 16 * 256 + 32);

#pragma unroll
        for (int kk = 0; kk < 8; ++kk) {
            if (kk + 2 < 8) {
                const int ko = (kk + 2) * 32;
#pragma unroll
                for (int i = 0; i < 4; ++i)
                    af[(kk + 2) % 3][i] = *(const bf16x8*)(arow + (size_t)i * 16 * 256 + ko);
            }
            bf16x8 bfv[4];
#pragma unroll
            for (int j = 0; j < 4; ++j)
                bfv[j] = *(const bf16x8*)(Bs + (size_t)((kk * 4 + kq) * 128 + wc + j * 16 + lr) * 8);
#pragma unroll
            for (int i = 0; i < 4; ++i)
#pragma unroll
                for (int j = 0; j < 4; ++j)
                    acc[i][j] = __builtin_amdgcn_mfma_f32_16x16x32_bf16(af[kk % 3][i], bfv[j], acc[i][j], 0, 0, 0);
        }

        // C/D layout: col=lane&15, row=(lane>>4)*4+reg  [m89-verified]
#pragma unroll
        for (int i = 0; i < 4; ++i) {
            const int rbase = row0 + wr + i * 16 + (lane >> 4) * 4;
#pragma unroll
            for (int j = 0; j < 4; ++j) {
                const int col = col00 + wc + j * 16 + lr;
                const float bv = bias[col];
#pragma unroll
                for (int r = 0; r < 4; ++r) {
                    const int row = rbase + r;
                    float v = acc[i][j][r] + bv;
                    if (EPI == 1) {
                        v += res[(size_t)row * N + col];
                        ((float*)outp)[(size_t)row * N + col] = v;
                    } else {
                        if (EPI == 2) v = gelu_fast(v);
                        ((u16*)outp)[(size_t)row * N + col] = f2bf(v);
                    }
                }
            }
        }
    }
}

// ---------------------------------------------------------------------------
// GEMM (round-5/8 structure) for K=1024 (fc2) and K=768 (conv).
// EPI 1: +bias+res(f32), f32 out    3: plain, bf16 out
// ---------------------------------------------------------------------------
template<int EPI>
__global__ __launch_bounds__(256) void gemm_kernel(
    const u16* __restrict__ A, const u16* __restrict__ Wt,
    const float* __restrict__ bias, const float* __restrict__ res,
    void* __restrict__ outp, int M, int N, int K)
{
    __shared__ __align__(16) u16 As[128 * 32];
    __shared__ __align__(16) u16 Bs[128 * 32];
    const int tid  = threadIdx.x;
    const int lane = tid & 63;
    const int wave = tid >> 6;
    const int row0 = blockIdx.x * 128;
    const int col0 = blockIdx.y * 128;
    const int wr = (wave >> 1) * 64;
    const int wc = (wave & 1) * 64;
    const int lr = lane & 15;
    const int kq = (lane >> 4) * 8;

    f32x4 acc[4][4];
#pragma unroll
    for (int i = 0; i < 4; ++i)
#pragma unroll
        for (int j = 0; j < 4; ++j) acc[i][j] = (f32x4){0.f, 0.f, 0.f, 0.f};

    const int srow = tid >> 2;
    const int scol = (tid & 3) * 8;
    const u16* ag = A  + (size_t)(row0 + srow) * K + scol;
    const u16* bg = Wt + (size_t)(col0 + srow) * K + scol;
    const size_t rstep = (size_t)64 * K;
    u16* alp = As + tid * 8;
    u16* blp = Bs + tid * 8;

    for (int k0 = 0; k0 < K; k0 += 32) {
        __syncthreads();
        load_lds16(ag + k0,         alp);
        load_lds16(ag + rstep + k0, alp + 64 * 32);
        load_lds16(bg + k0,         blp);
        load_lds16(bg + rstep + k0, blp + 64 * 32);
        __syncthreads();
        bf16x8 af[4], bfv[4];
#pragma unroll
        for (int i = 0; i < 4; ++i) af[i]  = *(const bf16x8*)(As + (wr + i * 16 + lr) * 32 + kq);
#pragma unroll
        for (int j = 0; j < 4; ++j) bfv[j] = *(const bf16x8*)(Bs + (wc + j * 16 + lr) * 32 + kq);
#pragma unroll
        for (int i = 0; i < 4; ++i)
#pragma unroll
            for (int j = 0; j < 4; ++j)
                acc[i][j] = __builtin_amdgcn_mfma_f32_16x16x32_bf16(af[i], bfv[j], acc[i][j], 0, 0, 0);
    }

#pragma unroll
    for (int i = 0; i < 4; ++i) {
        const int rbase = row0 + wr + i * 16 + (lane >> 4) * 4;
#pragma unroll
        for (int j = 0; j < 4; ++j) {
            const int col = col0 + wc + j * 16 + lr;
            const float bv = (EPI == 3) ? 0.f : bias[col];
#pragma unroll
            for (int r = 0; r < 4; ++r) {
                const int row = rbase + r;
                float v = acc[i][j][r] + bv;
                if (EPI == 1) {
                    v += res[(size_t)row * N + col];
                    ((float*)outp)[(size_t)row * N + col] = v;
                } else {
                    ((u16*)outp)[(size_t)row * N + col] = f2bf(v);
                }
            }
        }
    }
}

// ---------------------------------------------------------------------------
// weight swizzle: fp32 (D,K,N) -> bf16 panels (gemm3 layout)
// group g=((d*(N/128)+p)*(K/8)+kqq)*128+nl holds W[d][kqq*8..+8][p*128+nl]
// ---------------------------------------------------------------------------
__global__ void wswz_kernel(const float* __restrict__ in, u16* __restrict__ out,
                            int K, int N, int total)
{
    int g = blockIdx.x * 256 + threadIdx.x;
    if (g >= total) return;
    int nl  = g & 127;
    int t   = g >> 7;
    int kqq = t % (K >> 3);
    int dp  = t / (K >> 3);
    int p   = dp % (N >> 7);
    int d   = dp / (N >> 7);
    int n_g = p * 128 + nl;
    int k0  = kqq * 8;
    const float* s = in + ((size_t)d * K + k0) * N + n_g;
    u16 o[8];
#pragma unroll
    for (int e = 0; e < 8; ++e) o[e] = f2bf(s[(size_t)e * N]);
    *(uint4*)(out + (size_t)g * 8) = *(const uint4*)o;
}

// weight prep for old kernel: fp32 (batch,K,N) -> bf16 (batch,N,K)
__global__ void transpose_kernel(const float* __restrict__ in, u16* __restrict__ out,
                                 int K, int N, int total)
{
    int idx = blockIdx.x * 256 + threadIdx.x;
    if (idx >= total) return;
    int k = idx % K;
    int n = (idx / K) % N;
    int d = idx / (K * N);
    out[idx] = f2bf(in[(size_t)d * K * N + (size_t)k * N + n]);
}

// conv_w fp32 (512,256,3)[co][ci][t] -> bf16 (512,768) [co][t*256+ci]
__global__ void convw_kernel(const float* __restrict__ in, u16* __restrict__ out)
{
    int idx = blockIdx.x * 256 + threadIdx.x;
    int r  = idx % 768;
    int co = idx / 768;
    int t  = r / 256;
    int ci = r % 256;
    out[idx] = f2bf(in[(size_t)co * 768 + (size_t)ci * 3 + t]);
}

// ---------------------------------------------------------------------------
// LN fp32-in -> bf16-out, C=256 (wave per row, 4 rows/block)
// ---------------------------------------------------------------------------
__global__ __launch_bounds__(256) void ln_f2b_kernel(
    const float* __restrict__ x, const float* __restrict__ g,
    const float* __restrict__ be, u16* __restrict__ out)
{
    const int lane = threadIdx.x & 63;
    const int row  = blockIdx.x * 4 + (threadIdx.x >> 6);
    const float4 a = *(const float4*)(x + (size_t)row * 256 + lane * 4);
    float v[4] = {a.x, a.y, a.z, a.w};
    float s = v[0] + v[1] + v[2] + v[3];
#pragma unroll
    for (int m = 1; m < 64; m <<= 1) s += __shfl_xor(s, m);
    const float mean = s * (1.f / 256.f);
    float s2 = 0.f;
#pragma unroll
    for (int e = 0; e < 4; ++e) { float d = v[e] - mean; s2 += d * d; }
#pragma unroll
    for (int m = 1; m < 64; m <<= 1) s2 += __shfl_xor(s2, m);
    const float rstd = rsqrtf(s2 * (1.f / 256.f) + 1e-5f);
    const float4 gg = *(const float4*)(g + lane * 4);
    const float4 bb = *(const float4*)(be + lane * 4);
    ushort4 o;
    o.x = f2bf((v[0] - mean) * rstd * gg.x + bb.x);
    o.y = f2bf((v[1] - mean) * rstd * gg.y + bb.y);
    o.z = f2bf((v[2] - mean) * rstd * gg.z + bb.z);
    o.w = f2bf((v[3] - mean) * rstd * gg.w + bb.w);
    *(ushort4*)(out + (size_t)row * 256 + lane * 4) = o;
}

// ---------------------------------------------------------------------------
// LN bf16-in -> fp32-out, C=512 (wave per row, 4 rows/block)
// ---------------------------------------------------------------------------
__global__ __launch_bounds__(256) void ln_b2f_kernel(
    const u16* __restrict__ x, const float* __restrict__ g,
    const float* __restrict__ be, float* __restrict__ out)
{
    const int lane = threadIdx.x & 63;
    const int row  = blockIdx.x * 4 + (threadIdx.x >> 6);
    const u16* xr = x + (size_t)row * 512 + lane * 8;
    float v[8];
#pragma unroll
    for (int e = 0; e < 8; e += 4) {
        ushort4 a = *(const ushort4*)(xr + e);
        v[e] = bf2f(a.x); v[e+1] = bf2f(a.y); v[e+2] = bf2f(a.z); v[e+3] = bf2f(a.w);
    }
    float s = 0.f;
#pragma unroll
    for (int e = 0; e < 8; ++e) s += v[e];
#pragma unroll
    for (int m = 1; m < 64; m <<= 1) s += __shfl_xor(s, m);
    const float mean = s * (1.f / 512.f);
    float s2 = 0.f;
#pragma unroll
    for (int e = 0; e < 8; ++e) { float d = v[e] - mean; s2 += d * d; }
#pragma unroll
    for (int m = 1; m < 64; m <<= 1) s2 += __shfl_xor(s2, m);
    const float rstd = rsqrtf(s2 * (1.f / 512.f) + 1e-5f);
    float* orow = out + (size_t)row * 512 + lane * 8;
#pragma unroll
    for (int e = 0; e < 8; e += 4) {
        float4 o;
        o.x = (v[e]   - mean) * rstd * g[lane*8+e]   + be[lane*8+e];
        o.y = (v[e+1] - mean) * rstd * g[lane*8+e+1] + be[lane*8+e+1];
        o.z = (v[e+2] - mean) * rstd * g[lane*8+e+2] + be[lane*8+e+2];
        o.w = (v[e+3] - mean) * rstd * g[lane*8+e+3] + be[lane*8+e+3];
        *(float4*)(orow + e) = o;
    }
}

// ---------------------------------------------------------------------------
// NAT attention: wave per token, 8 heads x 8 lanes, HD=32 (4 dims/lane), K=7
// ---------------------------------------------------------------------------
__global__ __launch_bounds__(256) void attn_kernel(
    const u16* __restrict__ qkv, u16* __restrict__ out)
{
    const int lane  = threadIdx.x & 63;
    const int token = blockIdx.x * 4 + (threadIdx.x >> 6);
    const int b = token >> 11;
    const int l = token & 2047;
    const int h = lane >> 3;
    const int s = lane & 7;
    const int off = h * 32 + s * 4;

    ushort4 q4 = *(const ushort4*)(qkv + (size_t)token * 768 + off);
    const float scale = 0.17677669529663687f;  // 32^-0.5
    float q0 = bf2f(q4.x), q1 = bf2f(q4.y), q2 = bf2f(q4.z), q3 = bf2f(q4.w);

    int start = l - 3;
    start = start < 0 ? 0 : (start > 2041 ? 2041 : start);
    const u16* kbase = qkv + ((size_t)(b << 11) + start) * 768 + 256 + off;

    float sc[7], vv[7][4];
#pragma unroll
    for (int j = 0; j < 7; ++j) {
        const u16* kp = kbase + (size_t)j * 768;
        ushort4 k4 = *(const ushort4*)kp;
        ushort4 v4 = *(const ushort4*)(kp + 256);
        float d = q0 * bf2f(k4.x) + q1 * bf2f(k4.y) + q2 * bf2f(k4.z) + q3 * bf2f(k4.w);
        d += __shfl_xor(d, 1); d += __shfl_xor(d, 2); d += __shfl_xor(d, 4);
        sc[j] = d * scale;
        vv[j][0] = bf2f(v4.x); vv[j][1] = bf2f(v4.y); vv[j][2] = bf2f(v4.z); vv[j][3] = bf2f(v4.w);
    }
    float mx = sc[0];
#pragma unroll
    for (int j = 1; j < 7; ++j) mx = fmaxf(mx, sc[j]);
    float p[7], sum = 0.f;
#pragma unroll
    for (int j = 0; j < 7; ++j) { p[j] = expf(sc[j] - mx); sum += p[j]; }
    const float inv = 1.f / sum;
    float o0 = 0, o1 = 0, o2 = 0, o3 = 0;
#pragma unroll
    for (int j = 0; j < 7; ++j) {
        o0 += p[j] * vv[j][0]; o1 += p[j] * vv[j][1];
        o2 += p[j] * vv[j][2]; o3 += p[j] * vv[j][3];
    }
    ushort4 o;
    o.x = f2bf(o0 * inv); o.y = f2bf(o1 * inv); o.z = f2bf(o2 * inv); o.w = f2bf(o3 * inv);
    *(ushort4*)(out + (size_t)token * 256 + off) = o;
}

// im2col chunk: x2[rl][t*256+ci] = bf16(x[b, 2*lo+t-1, ci]), fp32 source
__global__ __launch_bounds__(256) void im2col_kernel(
    const float* __restrict__ x, u16* __restrict__ x2, int r0)
{
    int idx = blockIdx.x * 256 + threadIdx.x;
    int c4  = idx & 63;
    int t   = (idx >> 6) % 3;
    int rl  = idx / 192;
    int row = r0 + rl;
    int b   = row >> 10;
    int lo  = row & 1023;
    int l   = 2 * lo + t - 1;
    ushort4 o = {0, 0, 0, 0};
    if (l >= 0 && l < 2048) {
        float4 val = *(const float4*)(x + ((size_t)(b << 11) + l) * 256 + c4 * 4);
        o.x = f2bf(val.x); o.y = f2bf(val.y); o.z = f2bf(val.z); o.w = f2bf(val.w);
    }
    *(ushort4*)(x2 + (size_t)rl * 768 + t * 256 + c4 * 4) = o;
}

// ---------------------------------------------------------------------------
extern "C" void kernel_launch(void* const* d_in, const int* in_sizes, int n_in,
                              void* d_out, int out_size, void* d_ws, size_t ws_size,
                              hipStream_t stream)
{
    const float* x_in   = (const float*)d_in[0];
    const float* ln1_g  = (const float*)d_in[1];
    const float* ln1_b  = (const float*)d_in[2];
    const float* qkv_w  = (const float*)d_in[3];
    const float* qkv_b  = (const float*)d_in[4];
    const float* proj_w = (const float*)d_in[5];
    const float* proj_b = (const float*)d_in[6];
    const float* ln2_g  = (const float*)d_in[7];
    const float* ln2_b  = (const float*)d_in[8];
    const float* fc1_w  = (const float*)d_in[9];
    const float* fc1_b  = (const float*)d_in[10];
    const float* fc2_w  = (const float*)d_in[11];
    const float* fc2_b  = (const float*)d_in[12];
    const float* conv_w = (const float*)d_in[13];
    const float* dn_g   = (const float*)d_in[14];
    const float* dn_b   = (const float*)d_in[15];

    // d_out fp32: y [0, 8388608), x [8388608, 16777216). Running x in-place;
    // bf16 LN scratch xn borrows the y region (last written).
    float* xbuf = (float*)d_out + 8388608;
    u16*   xn   = (u16*)d_out;

    char* ws = (char*)d_ws;
    const size_t MB = 1024ull * 1024;
    u16* qkv_wt  = (u16*)ws;                  // 2x768x256 swz (0.75 MB)
    u16* proj_wt = qkv_wt  + 2 * 768 * 256;   // 2x256x256 swz
    u16* fc1_wt  = proj_wt + 2 * 256 * 256;   // 2x1024x256 swz
    u16* fc2_wt  = fc1_wt  + 2 * 1024 * 256;  // 2x256x1024 plain N,K
    u16* conv_wt = fc2_wt  + 2 * 256 * 1024;  // 512x768 plain
    u16* S       = (u16*)(ws + 4 * MB);       // chunk scratch

    const size_t R = ws_size > 4 * MB ? ws_size - 4 * MB : 0;
    int nb = 16;    while (nb > 1 && (size_t)nb * 4 * MB > R) nb >>= 1;     // qkv chunk (batches)
    int Mf = 32768; while (Mf > 2048 && (size_t)Mf * 2048 > R) Mf >>= 1;    // mlp rows
    int Mc = 16384; while (Mc > 2048 && (size_t)Mc * 2560 > R) Mc >>= 1;    // conv rows

    wswz_kernel<<<(2*256*768/8 + 255) / 256, 256, 0, stream>>>(qkv_w,  qkv_wt,  256, 768,  2*256*768/8);
    wswz_kernel<<<(2*256*256/8 + 255) / 256, 256, 0, stream>>>(proj_w, proj_wt, 256, 256,  2*256*256/8);
    wswz_kernel<<<(2*256*1024/8 + 255) / 256, 256, 0, stream>>>(fc1_w, fc1_wt,  256, 1024, 2*256*1024/8);
    transpose_kernel<<<(2*1024*256 + 255) / 256, 256, 0, stream>>>(fc2_w, fc2_wt, 1024, 256, 2*1024*256);
    convw_kernel<<<(512*768) / 256, 256, 0, stream>>>(conv_w, conv_wt);

    hipMemcpyAsync(xbuf, x_in, 32768ull * 256 * 4, hipMemcpyDeviceToDevice, stream);

    for (int layer = 0; layer < 2; ++layer) {
        const float* l1g = ln1_g + layer * 256;
        const float* l1b = ln1_b + layer * 256;
        const float* l2g = ln2_g + layer * 256;
        const float* l2b = ln2_b + layer * 256;
        const u16*   qwt = qkv_wt  + (size_t)layer * 768 * 256;
        const float* qb  = qkv_b   + layer * 768;
        const u16*   pwt = proj_wt + (size_t)layer * 256 * 256;
        const float* pb  = proj_b  + layer * 256;
        const u16*   f1w = fc1_wt  + (size_t)layer * 1024 * 256;
        const float* f1b = fc1_b   + layer * 1024;
        const u16*   f2w = fc2_wt  + (size_t)layer * 256 * 1024;
        const float* f2b = fc2_b   + layer * 256;

        ln_f2b_kernel<<<8192, 256, 0, stream>>>(xbuf, l1g, l1b, xn);
        {
            const int Mg = nb * 2048;
            u16* qkvc  = S;
            u16* atnoc = S + (size_t)Mg * 768;
            for (int g = 0; g < 16 / nb; ++g) {
                const size_t t0 = (size_t)g * Mg;
                gemm3_kernel<4, 0><<<dim3(Mg / 512, 6), 256, 0, stream>>>(
                    xn + t0 * 256, qwt, qb, nullptr, qkvc, Mg, 768);
                attn_kernel<<<Mg / 4, 256, 0, stream>>>(qkvc, atnoc);
                gemm3_kernel<2, 1><<<dim3(Mg / 256, 2), 256, 0, stream>>>(
                    atnoc, pwt, pb, xbuf + t0 * 256, xbuf + t0 * 256, Mg, 256);
            }
        }
        ln_f2b_kernel<<<8192, 256, 0, stream>>>(xbuf, l2g, l2b, xn);
        {
            u16* hbuf = S;
            for (int q = 0; q < 32768 / Mf; ++q) {
                const size_t r0 = (size_t)q * Mf;
                gemm3_kernel<4, 2><<<dim3(Mf / 512, 8), 256, 0, stream>>>(
                    xn + r0 * 256, f1w, f1b, nullptr, hbuf, Mf, 1024);
                gemm_kernel<1><<<dim3(Mf / 128, 2), 256, 0, stream>>>(
                    hbuf, f2w, f2b, xbuf + r0 * 256, xbuf + r0 * 256, Mf, 256, 1024);
            }
        }
    }

    // downsample conv (im2col GEMM) + final LN -> fp32 y, chunked
    {
        u16* x2c = S;
        u16* ycc = S + (size_t)Mc * 768;
        for (int c = 0; c < 16384 / Mc; ++c) {
            const int r0 = c * Mc;
            im2col_kernel<<<3 * Mc / 4, 256, 0, stream>>>(xbuf, x2c, r0);
            gemm_kernel<3><<<dim3(Mc / 128, 4), 256, 0, stream>>>(
                x2c, conv_wt, nullptr, nullptr, ycc, Mc, 512, 768);
            ln_b2f_kernel<<<Mc / 4, 256, 0, stream>>>(
                ycc, dn_g, dn_b, (float*)d_out + (size_t)r0 * 512);
        }
    }
    // x output already in place (xbuf aliases d_out's x-region)
}

// Round 10
// 501.025 us; speedup vs baseline: 1.0884x; 1.0884x over previous
//
#include <hip/hip_runtime.h>

typedef unsigned short u16;
typedef __attribute__((ext_vector_type(8))) short bf16x8;
typedef __attribute__((ext_vector_type(4))) float f32x4;

__device__ __forceinline__ float bf2f(u16 u) { return __uint_as_float(((unsigned)u) << 16); }
__device__ __forceinline__ u16 f2bf(float f) {
    unsigned u = __float_as_uint(f);
    return (u16)((u + 0x7FFFu + ((u >> 16) & 1u)) >> 16);
}

// fast GELU (tanh form): v * sigmoid(1.5957691*v + 0.07135481*v^3)
__device__ __forceinline__ float gelu_fast(float v) {
    float u = v * (1.5957691216057308f + 0.07135481282700722f * v * v);
    return v * (1.f / (1.f + __expf(-u)));
}

// async global->LDS, 16 B per lane. LDS dest = wave-uniform base + lane*16.
__device__ __forceinline__ void load_lds16(const u16* g, u16* l) {
    __builtin_amdgcn_global_load_lds(
        (const __attribute__((address_space(1))) unsigned int*)g,
        (__attribute__((address_space(3))) unsigned int*)l,
        16, 0, 0);
}

// ---------------------------------------------------------------------------
// GEMM (round-8 2-barrier structure, BK=64, XOR-swizzled LDS):
// out = A(MxK) @ Wt(NxK)^T, bf16 in, fp32 acc.  K % 64 == 0.
// LDS tile layout: 16B-slot(row, chunk) = row*8 + (chunk ^ (row&7)); the
// swizzle lives in the *global source* address (per-lane free) so the
// lane-contiguous global_load_lds constraint is satisfied, and ds_read_b128
// frag reads are 2-way-max bank aliased (free, m136).
// BK=64 halves the barrier/vmcnt(0) drain count vs BK=32.
// EPI 0: +bias, bf16 out   1: +bias+res(f32), f32 out
//     2: +bias+gelu_fast, bf16 out   3: plain, bf16 out
// ---------------------------------------------------------------------------
template<int EPI>
__global__ __launch_bounds__(256) void gemm_kernel(
    const u16* __restrict__ A, const u16* __restrict__ Wt,
    const float* __restrict__ bias, const float* __restrict__ res,
    void* __restrict__ outp, int M, int N, int K)
{
    __shared__ __align__(16) u16 As[128 * 64];   // 16 KB each, swizzled
    __shared__ __align__(16) u16 Bs[128 * 64];
    const int tid  = threadIdx.x;
    const int lane = tid & 63;
    const int wave = tid >> 6;
    const int row0 = blockIdx.x * 128;
    const int col0 = blockIdx.y * 128;
    const int wr = (wave >> 1) * 64;
    const int wc = (wave & 1) * 64;
    const int lr = lane & 15;
    const int q  = lane >> 4;            // 0..3

    f32x4 acc[4][4];
#pragma unroll
    for (int i = 0; i < 4; ++i)
#pragma unroll
        for (int j = 0; j < 4; ++j) acc[i][j] = (f32x4){0.f, 0.f, 0.f, 0.f};

    // staging: thread t -> row t>>3 (+32/sweep), source chunk (t&7)^((t>>3)&7)
    // LDS slot t (+256/sweep) == row*8 + (chunk ^ (row&7))  [32 = 0 mod 8]
    const int strow  = tid >> 3;                      // 0..31
    const int schunk = (tid & 7) ^ (strow & 7);
    const u16* ag = A  + (size_t)(row0 + strow) * K + schunk * 8;
    const u16* bg = Wt + (size_t)(col0 + strow) * K + schunk * 8;
    const size_t rstep32 = (size_t)32 * K;
    u16* alp = As + tid * 8;
    u16* blp = Bs + tid * 8;

    for (int k0 = 0; k0 < K; k0 += 64) {
        __syncthreads();                 // prev iter's LDS reads complete
#pragma unroll
        for (int s = 0; s < 4; ++s) {
            load_lds16(ag + s * rstep32 + k0, alp + s * 2048);
            load_lds16(bg + s * rstep32 + k0, blp + s * 2048);
        }
        __syncthreads();                 // vmcnt(0) drain: tiles resident
#pragma unroll
        for (int kk = 0; kk < 2; ++kk) {
            bf16x8 af[4], bfv[4];
#pragma unroll
            for (int i = 0; i < 4; ++i) {
                const int r = wr + i * 16 + lr;
                af[i] = *(const bf16x8*)(As + r * 64 + (((kk * 4 + q) ^ (r & 7)) * 8));
            }
#pragma unroll
            for (int j = 0; j < 4; ++j) {
                const int r = wc + j * 16 + lr;
                bfv[j] = *(const bf16x8*)(Bs + r * 64 + (((kk * 4 + q) ^ (r & 7)) * 8));
            }
#pragma unroll
            for (int i = 0; i < 4; ++i)
#pragma unroll
                for (int j = 0; j < 4; ++j)
                    acc[i][j] = __builtin_amdgcn_mfma_f32_16x16x32_bf16(af[i], bfv[j], acc[i][j], 0, 0, 0);
        }
    }

    // C/D layout: col=lane&15, row=(lane>>4)*4+reg  [m89-verified]
#pragma unroll
    for (int i = 0; i < 4; ++i) {
        const int rbase = row0 + wr + i * 16 + (lane >> 4) * 4;
#pragma unroll
        for (int j = 0; j < 4; ++j) {
            const int col = col0 + wc + j * 16 + lr;
            const float bv = (EPI == 3) ? 0.f : bias[col];
#pragma unroll
            for (int r = 0; r < 4; ++r) {
                const int row = rbase + r;
                float v = acc[i][j][r] + bv;
                if (EPI == 1) {
                    v += res[(size_t)row * N + col];
                    ((float*)outp)[(size_t)row * N + col] = v;
                } else {
                    if (EPI == 2) v = gelu_fast(v);
                    ((u16*)outp)[(size_t)row * N + col] = f2bf(v);
                }
            }
        }
    }
}

// ---------------------------------------------------------------------------
// LN fp32-in -> bf16-out, C=256 (wave per row, 4 rows/block)
// ---------------------------------------------------------------------------
__global__ __launch_bounds__(256) void ln_f2b_kernel(
    const float* __restrict__ x, const float* __restrict__ g,
    const float* __restrict__ be, u16* __restrict__ out)
{
    const int lane = threadIdx.x & 63;
    const int row  = blockIdx.x * 4 + (threadIdx.x >> 6);
    const float4 a = *(const float4*)(x + (size_t)row * 256 + lane * 4);
    float v[4] = {a.x, a.y, a.z, a.w};
    float s = v[0] + v[1] + v[2] + v[3];
#pragma unroll
    for (int m = 1; m < 64; m <<= 1) s += __shfl_xor(s, m);
    const float mean = s * (1.f / 256.f);
    float s2 = 0.f;
#pragma unroll
    for (int e = 0; e < 4; ++e) { float d = v[e] - mean; s2 += d * d; }
#pragma unroll
    for (int m = 1; m < 64; m <<= 1) s2 += __shfl_xor(s2, m);
    const float rstd = rsqrtf(s2 * (1.f / 256.f) + 1e-5f);
    const float4 gg = *(const float4*)(g + lane * 4);
    const float4 bb = *(const float4*)(be + lane * 4);
    ushort4 o;
    o.x = f2bf((v[0] - mean) * rstd * gg.x + bb.x);
    o.y = f2bf((v[1] - mean) * rstd * gg.y + bb.y);
    o.z = f2bf((v[2] - mean) * rstd * gg.z + bb.z);
    o.w = f2bf((v[3] - mean) * rstd * gg.w + bb.w);
    *(ushort4*)(out + (size_t)row * 256 + lane * 4) = o;
}

// ---------------------------------------------------------------------------
// LN bf16-in -> fp32-out, C=512 (wave per row, 4 rows/block)
// ---------------------------------------------------------------------------
__global__ __launch_bounds__(256) void ln_b2f_kernel(
    const u16* __restrict__ x, const float* __restrict__ g,
    const float* __restrict__ be, float* __restrict__ out)
{
    const int lane = threadIdx.x & 63;
    const int row  = blockIdx.x * 4 + (threadIdx.x >> 6);
    const u16* xr = x + (size_t)row * 512 + lane * 8;
    float v[8];
#pragma unroll
    for (int e = 0; e < 8; e += 4) {
        ushort4 a = *(const ushort4*)(xr + e);
        v[e] = bf2f(a.x); v[e+1] = bf2f(a.y); v[e+2] = bf2f(a.z); v[e+3] = bf2f(a.w);
    }
    float s = 0.f;
#pragma unroll
    for (int e = 0; e < 8; ++e) s += v[e];
#pragma unroll
    for (int m = 1; m < 64; m <<= 1) s += __shfl_xor(s, m);
    const float mean = s * (1.f / 512.f);
    float s2 = 0.f;
#pragma unroll
    for (int e = 0; e < 8; ++e) { float d = v[e] - mean; s2 += d * d; }
#pragma unroll
    for (int m = 1; m < 64; m <<= 1) s2 += __shfl_xor(s2, m);
    const float rstd = rsqrtf(s2 * (1.f / 512.f) + 1e-5f);
    float* orow = out + (size_t)row * 512 + lane * 8;
#pragma unroll
    for (int e = 0; e < 8; e += 4) {
        float4 o;
        o.x = (v[e]   - mean) * rstd * g[lane*8+e]   + be[lane*8+e];
        o.y = (v[e+1] - mean) * rstd * g[lane*8+e+1] + be[lane*8+e+1];
        o.z = (v[e+2] - mean) * rstd * g[lane*8+e+2] + be[lane*8+e+2];
        o.w = (v[e+3] - mean) * rstd * g[lane*8+e+3] + be[lane*8+e+3];
        *(float4*)(orow + e) = o;
    }
}

// ---------------------------------------------------------------------------
// NAT attention: wave per token, 8 heads x 8 lanes, HD=32 (4 dims/lane), K=7
// ---------------------------------------------------------------------------
__global__ __launch_bounds__(256) void attn_kernel(
    const u16* __restrict__ qkv, u16* __restrict__ out)
{
    const int lane  = threadIdx.x & 63;
    const int token = blockIdx.x * 4 + (threadIdx.x >> 6);
    const int b = token >> 11;
    const int l = token & 2047;
    const int h = lane >> 3;
    const int s = lane & 7;
    const int off = h * 32 + s * 4;

    ushort4 q4 = *(const ushort4*)(qkv + (size_t)token * 768 + off);
    const float scale = 0.17677669529663687f;  // 32^-0.5
    float q0 = bf2f(q4.x), q1 = bf2f(q4.y), q2 = bf2f(q4.z), q3 = bf2f(q4.w);

    int start = l - 3;
    start = start < 0 ? 0 : (start > 2041 ? 2041 : start);
    const u16* kbase = qkv + ((size_t)(b << 11) + start) * 768 + 256 + off;

    float sc[7], vv[7][4];
#pragma unroll
    for (int j = 0; j < 7; ++j) {
        const u16* kp = kbase + (size_t)j * 768;
        ushort4 k4 = *(const ushort4*)kp;
        ushort4 v4 = *(const ushort4*)(kp + 256);
        float d = q0 * bf2f(k4.x) + q1 * bf2f(k4.y) + q2 * bf2f(k4.z) + q3 * bf2f(k4.w);
        d += __shfl_xor(d, 1); d += __shfl_xor(d, 2); d += __shfl_xor(d, 4);
        sc[j] = d * scale;
        vv[j][0] = bf2f(v4.x); vv[j][1] = bf2f(v4.y); vv[j][2] = bf2f(v4.z); vv[j][3] = bf2f(v4.w);
    }
    float mx = sc[0];
#pragma unroll
    for (int j = 1; j < 7; ++j) mx = fmaxf(mx, sc[j]);
    float p[7], sum = 0.f;
#pragma unroll
    for (int j = 0; j < 7; ++j) { p[j] = expf(sc[j] - mx); sum += p[j]; }
    const float inv = 1.f / sum;
    float o0 = 0, o1 = 0, o2 = 0, o3 = 0;
#pragma unroll
    for (int j = 0; j < 7; ++j) {
        o0 += p[j] * vv[j][0]; o1 += p[j] * vv[j][1];
        o2 += p[j] * vv[j][2]; o3 += p[j] * vv[j][3];
    }
    ushort4 o;
    o.x = f2bf(o0 * inv); o.y = f2bf(o1 * inv); o.z = f2bf(o2 * inv); o.w = f2bf(o3 * inv);
    *(ushort4*)(out + (size_t)token * 256 + off) = o;
}

// ---------------------------------------------------------------------------
// weight prep: fp32 (batch,K,N) -> bf16 (batch,N,K)
// ---------------------------------------------------------------------------
__global__ void transpose_kernel(const float* __restrict__ in, u16* __restrict__ out,
                                 int K, int N, int total)
{
    int idx = blockIdx.x * 256 + threadIdx.x;
    if (idx >= total) return;
    int k = idx % K;
    int n = (idx / K) % N;
    int d = idx / (K * N);
    out[idx] = f2bf(in[(size_t)d * K * N + (size_t)k * N + n]);
}

// conv_w fp32 (512,256,3) [co][ci][t] -> bf16 (512,768) [co][t*256+ci]
__global__ void convw_kernel(const float* __restrict__ in, u16* __restrict__ out)
{
    int idx = blockIdx.x * 256 + threadIdx.x;
    int r  = idx % 768;
    int co = idx / 768;
    int t  = r / 256;
    int ci = r % 256;
    out[idx] = f2bf(in[(size_t)co * 768 + (size_t)ci * 3 + t]);
}

// im2col chunk: x2[rl][t*256+ci] = bf16(x[b, 2*lo+t-1, ci]), fp32 source
__global__ __launch_bounds__(256) void im2col_kernel(
    const float* __restrict__ x, u16* __restrict__ x2, int r0)
{
    int idx = blockIdx.x * 256 + threadIdx.x;
    int c4  = idx & 63;
    int t   = (idx >> 6) % 3;
    int rl  = idx / 192;
    int row = r0 + rl;
    int b   = row >> 10;
    int lo  = row & 1023;
    int l   = 2 * lo + t - 1;
    ushort4 o = {0, 0, 0, 0};
    if (l >= 0 && l < 2048) {
        float4 val = *(const float4*)(x + ((size_t)(b << 11) + l) * 256 + c4 * 4);
        o.x = f2bf(val.x); o.y = f2bf(val.y); o.z = f2bf(val.z); o.w = f2bf(val.w);
    }
    *(ushort4*)(x2 + (size_t)rl * 768 + t * 256 + c4 * 4) = o;
}

// ---------------------------------------------------------------------------
extern "C" void kernel_launch(void* const* d_in, const int* in_sizes, int n_in,
                              void* d_out, int out_size, void* d_ws, size_t ws_size,
                              hipStream_t stream)
{
    const float* x_in   = (const float*)d_in[0];
    const float* ln1_g  = (const float*)d_in[1];
    const float* ln1_b  = (const float*)d_in[2];
    const float* qkv_w  = (const float*)d_in[3];
    const float* qkv_b  = (const float*)d_in[4];
    const float* proj_w = (const float*)d_in[5];
    const float* proj_b = (const float*)d_in[6];
    const float* ln2_g  = (const float*)d_in[7];
    const float* ln2_b  = (const float*)d_in[8];
    const float* fc1_w  = (const float*)d_in[9];
    const float* fc1_b  = (const float*)d_in[10];
    const float* fc2_w  = (const float*)d_in[11];
    const float* fc2_b  = (const float*)d_in[12];
    const float* conv_w = (const float*)d_in[13];
    const float* dn_g   = (const float*)d_in[14];
    const float* dn_b   = (const float*)d_in[15];

    // d_out fp32: y [0, 8388608), x [8388608, 16777216). Running x in-place;
    // bf16 LN scratch xn borrows the y region (last written).
    float* xbuf = (float*)d_out + 8388608;
    u16*   xn   = (u16*)d_out;

    char* ws = (char*)d_ws;
    const size_t MB = 1024ull * 1024;
    u16* qkv_wt  = (u16*)ws;                  // 2x768x256  bf16 (0.75 MB)
    u16* proj_wt = qkv_wt  + 2 * 768 * 256;   // 2x256x256
    u16* fc1_wt  = proj_wt + 2 * 256 * 256;   // 2x1024x256
    u16* fc2_wt  = fc1_wt  + 2 * 1024 * 256;  // 2x256x1024
    u16* conv_wt = fc2_wt  + 2 * 256 * 1024;  // 512x768
    u16* S       = (u16*)(ws + 4 * MB);       // chunk scratch

    const size_t R = ws_size > 4 * MB ? ws_size - 4 * MB : 0;
    int nb = 16;    while (nb > 1 && (size_t)nb * 4 * MB > R) nb >>= 1;     // qkv chunk (batches)
    int Mf = 32768; while (Mf > 2048 && (size_t)Mf * 2048 > R) Mf >>= 1;    // mlp rows
    int Mc = 16384; while (Mc > 2048 && (size_t)Mc * 2560 > R) Mc >>= 1;    // conv rows

    transpose_kernel<<<(2*256*768 + 255) / 256, 256, 0, stream>>>(qkv_w,  qkv_wt,  256, 768, 2*256*768);
    transpose_kernel<<<(2*256*256 + 255) / 256, 256, 0, stream>>>(proj_w, proj_wt, 256, 256, 2*256*256);
    transpose_kernel<<<(2*256*1024 + 255) / 256, 256, 0, stream>>>(fc1_w, fc1_wt,  256, 1024, 2*256*1024);
    transpose_kernel<<<(2*1024*256 + 255) / 256, 256, 0, stream>>>(fc2_w, fc2_wt,  1024, 256, 2*1024*256);
    convw_kernel<<<(512*768) / 256, 256, 0, stream>>>(conv_w, conv_wt);

    hipMemcpyAsync(xbuf, x_in, 32768ull * 256 * 4, hipMemcpyDeviceToDevice, stream);

    for (int layer = 0; layer < 2; ++layer) {
        const float* l1g = ln1_g + layer * 256;
        const float* l1b = ln1_b + layer * 256;
        const float* l2g = ln2_g + layer * 256;
        const float* l2b = ln2_b + layer * 256;
        const u16*   qwt = qkv_wt  + (size_t)layer * 768 * 256;
        const float* qb  = qkv_b   + layer * 768;
        const u16*   pwt = proj_wt + (size_t)layer * 256 * 256;
        const float* pb  = proj_b  + layer * 256;
        const u16*   f1w = fc1_wt  + (size_t)layer * 1024 * 256;
        const float* f1b = fc1_b   + layer * 1024;
        const u16*   f2w = fc2_wt  + (size_t)layer * 256 * 1024;
        const float* f2b = fc2_b   + layer * 256;

        ln_f2b_kernel<<<8192, 256, 0, stream>>>(xbuf, l1g, l1b, xn);
        {
            const int Mg = nb * 2048;
            u16* qkvc  = S;
            u16* atnoc = S + (size_t)Mg * 768;
            for (int g = 0; g < 16 / nb; ++g) {
                const size_t t0 = (size_t)g * Mg;
                gemm_kernel<0><<<dim3(Mg / 128, 6), 256, 0, stream>>>(
                    xn + t0 * 256, qwt, qb, nullptr, qkvc, Mg, 768, 256);
                attn_kernel<<<Mg / 4, 256, 0, stream>>>(qkvc, atnoc);
                gemm_kernel<1><<<dim3(Mg / 128, 2), 256, 0, stream>>>(
                    atnoc, pwt, pb, xbuf + t0 * 256, xbuf + t0 * 256, Mg, 256, 256);
            }
        }
        ln_f2b_kernel<<<8192, 256, 0, stream>>>(xbuf, l2g, l2b, xn);
        {
            u16* hbuf = S;
            for (int q = 0; q < 32768 / Mf; ++q) {
                const size_t r0 = (size_t)q * Mf;
                gemm_kernel<2><<<dim3(Mf / 128, 8), 256, 0, stream>>>(
                    xn + r0 * 256, f1w, f1b, nullptr, hbuf, Mf, 1024, 256);
                gemm_kernel<1><<<dim3(Mf / 128, 2), 256, 0, stream>>>(
                    hbuf, f2w, f2b, xbuf + r0 * 256, xbuf + r0 * 256, Mf, 256, 1024);
            }
        }
    }

    // downsample conv (im2col GEMM) + final LN -> fp32 y, chunked
    {
        u16* x2c = S;
        u16* ycc = S + (size_t)Mc * 768;
        for (int c = 0; c < 16384 / Mc; ++c) {
            const int r0 = c * Mc;
            im2col_kernel<<<3 * Mc / 4, 256, 0, stream>>>(xbuf, x2c, r0);
            gemm_kernel<3><<<dim3(Mc / 128, 4), 256, 0, stream>>>(
                x2c, conv_wt, nullptr, nullptr, ycc, Mc, 512, 768);
            ln_b2f_kernel<<<Mc / 4, 256, 0, stream>>>(
                ycc, dn_g, dn_b, (float*)d_out + (size_t)r0 * 512);
        }
    }
    // x output already in place (xbuf aliases d_out's x-region)
}